// Round 13
// baseline (1383.413 us; speedup 1.0000x reference)
//
#include <hip/hip_runtime.h>
#include <cmath>

typedef unsigned short u16;
typedef unsigned int u32;
typedef __attribute__((ext_vector_type(8))) short short8;   // 8 x bf16 (4 VGPRs)
typedef __attribute__((ext_vector_type(4))) short short4v;  // 4 x bf16
typedef __attribute__((ext_vector_type(4))) float f32x4;

__device__ __forceinline__ float bf2f(u16 h) {
  union { u32 u; float f; } v; v.u = ((u32)h) << 16; return v.f;
}
__device__ __forceinline__ u16 f2bf(float f) {
  union { float f; u32 u; } v; v.f = f;
  u32 u = v.u;
  u32 r = (u + 0x7FFFu + ((u >> 16) & 1u)) >> 16;   // RNE
  return (u16)r;
}

// ---------------------------------------------------------------- conversions
__global__ void convw_kernel(const float* __restrict__ W, u16* __restrict__ Wt,
                             int K, int N, int Kp) {
  int k = blockIdx.x * 256 + threadIdx.x;
  int n = blockIdx.y;
  if (k >= Kp) return;
  float v = (k < K && n < N) ? W[(size_t)k * N + n] : 0.f;
  Wt[(size_t)n * Kp + k] = f2bf(v);
}

// ---------------------------------------------------------------- CSR build
__global__ void zero_kernel(int* p, int n) {
  int i = blockIdx.x * 256 + threadIdx.x;
  if (i < n) p[i] = 0;
}
__global__ void count_kernel(const int* __restrict__ rows, int* __restrict__ counts, int E) {
  int i = blockIdx.x * 256 + threadIdx.x;
  if (i < E) atomicAdd(&counts[rows[i]], 1);
}
__global__ __launch_bounds__(1024) void scan_kernel(const int* __restrict__ counts,
                                                    int* __restrict__ rowptr,
                                                    int* __restrict__ cursor, int n) {
  __shared__ int buf[1024];
  __shared__ int carry_s;
  int tid = threadIdx.x;
  if (tid == 0) carry_s = 0;
  __syncthreads();
  for (int base = 0; base < n; base += 1024) {
    int i = base + tid;
    int v = (i < n) ? counts[i] : 0;
    buf[tid] = v;
    __syncthreads();
    for (int off = 1; off < 1024; off <<= 1) {
      int tv = (tid >= off) ? buf[tid - off] : 0;
      __syncthreads();
      buf[tid] += tv;
      __syncthreads();
    }
    int incl = buf[tid];
    int carry = carry_s;
    if (i < n) { int ex = carry + incl - v; rowptr[i] = ex; cursor[i] = ex; }
    __syncthreads();
    if (tid == 1023) carry_s = carry + incl;
    __syncthreads();
  }
  if (tid == 0) rowptr[n] = carry_s;
}
__global__ void scatter_kernel(const int* __restrict__ rows, const int* __restrict__ cols,
                               const float* __restrict__ vals, int* __restrict__ cursor,
                               int* __restrict__ cols_s, float* __restrict__ vals_s, int E) {
  int i = blockIdx.x * 256 + threadIdx.x;
  if (i < E) {
    int r = rows[i];
    int p = atomicAdd(&cursor[r], 1);
    cols_s[p] = cols[i];
    vals_s[p] = vals[i];
  }
}

// ---------------------------------------------------------------- 128x128 bf16 GEMM (small layers)
#define BM 128
#define BN 128
#define BK 32

template <bool BIAS, bool RELU, bool OUTBF16, int CH>
__global__ __launch_bounds__(256, 2) void gemm_bf16(
    const u16* __restrict__ A, int lda, const u16* __restrict__ Bt, int ldb,
    void* __restrict__ C1, int ldc,
    const float* __restrict__ bias, int M, int Nreal, int K, int MT, int NT) {
  __shared__ __align__(16) u16 As[2][BM * BK];
  __shared__ __align__(16) u16 Bs[2][BN * BK];
  const int lin = blockIdx.x;
  const int per = CH * NT;
  const int g = lin / per;
  const int r0 = lin - g * per;
  const int bx0 = g * CH;
  const int cw = min(CH, MT - bx0);
  const int bx = bx0 + r0 % cw;
  const int by = r0 / cw;

  const int tid = threadIdx.x;
  const int lane = tid & 63;
  const int wave = tid >> 6;
  const int mblk = bx * BM;
  const int nblk = by * BN;
  const int wm = (wave & 1) * 64;
  const int wn = (wave >> 1) * 64;
  const int ml = lane & 15;
  const int kg = lane >> 4;

  f32x4 acc[4][4];
#pragma unroll
  for (int i = 0; i < 4; ++i)
#pragma unroll
    for (int j = 0; j < 4; ++j) acc[i][j] = (f32x4)(0.f);

  const int nk = K / BK;
  const int sr = tid >> 2;
  const int sc = (tid & 3) * 8;
  const u16* gA0 = A + (size_t)(mblk + sr) * lda + sc;
  const u16* gA1 = A + (size_t)(mblk + sr + 64) * lda + sc;
  const u16* gB0 = Bt + (size_t)(nblk + sr) * ldb + sc;
  const u16* gB1 = Bt + (size_t)(nblk + sr + 64) * ldb + sc;

  auto stage = [&](int buf, int kt) {
    const int ko = kt * BK;
    u16* lA = &As[buf][0] + wave * 512;
    u16* lB = &Bs[buf][0] + wave * 512;
    __builtin_amdgcn_global_load_lds((const void*)(gA0 + ko), (void*)lA, 16, 0, 0);
    __builtin_amdgcn_global_load_lds((const void*)(gA1 + ko), (void*)(lA + 2048), 16, 0, 0);
    __builtin_amdgcn_global_load_lds((const void*)(gB0 + ko), (void*)lB, 16, 0, 0);
    __builtin_amdgcn_global_load_lds((const void*)(gB1 + ko), (void*)(lB + 2048), 16, 0, 0);
  };

  stage(0, 0);
  asm volatile("s_waitcnt vmcnt(0)" ::: "memory");
  __syncthreads();

  int cur = 0;
  for (int kt = 0; kt < nk; ++kt) {
    if (kt + 1 < nk) stage(cur ^ 1, kt + 1);
    short8 af[4], bfr[4];
#pragma unroll
    for (int i = 0; i < 4; ++i) {
      af[i] = *(const short8*)&As[cur][(wm + i * 16 + ml) * BK + kg * 8];
      bfr[i] = *(const short8*)&Bs[cur][(wn + i * 16 + ml) * BK + kg * 8];
    }
#pragma unroll
    for (int i = 0; i < 4; ++i)
#pragma unroll
      for (int j = 0; j < 4; ++j)
        acc[i][j] = __builtin_amdgcn_mfma_f32_16x16x32_bf16(af[i], bfr[j], acc[i][j], 0, 0, 0);
    asm volatile("s_waitcnt vmcnt(0)" ::: "memory");
    __syncthreads();
    cur ^= 1;
  }

#pragma unroll
  for (int i = 0; i < 4; ++i) {
    const int row0 = mblk + wm + i * 16 + kg * 4;
#pragma unroll
    for (int j = 0; j < 4; ++j) {
      const int col = nblk + wn + j * 16 + ml;
      if (col < Nreal) {
        float bv = BIAS ? bias[col] : 0.f;
#pragma unroll
        for (int r = 0; r < 4; ++r) {
          const int row = row0 + r;
          if (row < M) {
            float v = acc[i][j][r] + bv;
            if (RELU) v = fmaxf(v, 0.f);
            if (OUTBF16)
              ((u16*)C1)[(size_t)row * ldc + col] = f2bf(v);
            else
              ((float*)C1)[(size_t)row * ldc + col] = v;
          }
        }
      }
    }
  }
}

// ---------------------------------------------------------------- 256x256 8-wave pipelined GEMM
// MODE 0: A is fp32 (x read DIRECTLY — convx/A0 eliminated). Reg-staged A (T14 split):
//   issue 8x float4/thread for kt+1 at kt start (BEFORE B gloads -> vmcnt FIFO retires A
//   first); at kt end: vmcnt(4) -> RNE cvt -> swizzled ds_write_b128 ->
//   vmcnt(0)+lgkmcnt(0) -> ONE barrier/tile (cross-wave LDS publish fenced).
//   Split bf16 out: cols<512 -> C1 (bias+relu), cols>=512 -> C2 (plain), ldc=512.
// MODE 1: bf16 A via gload_lds, fp32 out — byte-identical to round-12 passing code.
// LDS layout (u16 elements): A(d) at d*16384, B(d) at 32768 + d*16384.
template <int MODE>
__global__ __launch_bounds__(512, 1) void gemm256p(
    const u16* __restrict__ A, int lda, const u16* __restrict__ Bt, int ldb,
    void* __restrict__ C1, void* __restrict__ C2, int ldc,
    const float* __restrict__ bias, int M, int Nreal, int K, int MT2, int NT) {
  __shared__ __align__(16) u16 smem[2 * 2 * 256 * 64];   // 128 KiB
  const int tid = threadIdx.x;
  const int lane = tid & 63;
  const int wave = tid >> 6;
  const int wm = wave >> 2;        // 0..1
  const int wn = wave & 3;         // 0..3
  const int ml = lane & 15;
  const int kg = lane >> 4;

  const int grp = blockIdx.x / (8 * NT);
  const int rr = blockIdx.x % (8 * NT);
  const int nb = min(8, MT2 - grp * 8);
  const int bx = grp * 8 + rr % nb;
  const int by = rr / nb;
  const int mblk = bx * 256;
  const int nblk = by * 256;

  f32x4 acc[8][4];
#pragma unroll
  for (int i = 0; i < 8; ++i)
#pragma unroll
    for (int j = 0; j < 4; ++j) acc[i][j] = (f32x4)(0.f);

  const int srow = tid >> 3;
  const int clog = (tid & 7) ^ (srow & 7);
  const size_t bbase = (size_t)(nblk + srow) * ldb + clog * 8;
  const int NKT = K / 64;

  auto stageB = [&](int d, int kt, int h) {
    u16* dst = smem + 32768 + d * 16384 + h * 4096 + wave * 512;
    const u16* src = Bt + bbase + (size_t)h * 64 * ldb + kt * 64;
    __builtin_amdgcn_global_load_lds((const void*)src, (void*)dst, 16, 0, 0);
  };
  auto stageU0 = [&](int d, int kt) { stageB(d, kt, 0); stageB(d, kt, 1); };
  auto stageU1 = [&](int d, int kt) { stageB(d, kt, 2); stageB(d, kt, 3); };
  auto readA = [&](int d, int im, int kk) -> short8 {
    const int r = wm * 128 + im * 16 + ml;
    const int ch = (kk * 4 + kg) ^ (r & 7);
    return *(const short8*)&smem[d * 16384 + r * 64 + ch * 8];
  };
  auto readB = [&](int d, int j, int kk) -> short8 {
    const int r = wn * 64 + j * 16 + ml;
    const int ch = (kk * 4 + kg) ^ (r & 7);
    return *(const short8*)&smem[32768 + d * 16384 + r * 64 + ch * 8];
  };

  if constexpr (MODE == 0) {
    // ---- fp32-A reg-staged path ----
    const float* X = (const float*)A;         // [M][lda] fp32, lda real (3000)
    const int arow = tid >> 1;                // tile-local row 0..255
    const int ahalf = tid & 1;                // cols ahalf*32 .. +31 of 64-col slice
    const int growA = mblk + arow;
    const bool rowok = growA < M;
    const float* xrow = X + (size_t)growA * lda;
    float4 a4[8];

    auto issueA = [&](int kt) {
      const int k0 = kt * 64 + ahalf * 32;
      if (rowok && k0 + 32 <= lda) {
#pragma unroll
        for (int j = 0; j < 8; ++j) a4[j] = *(const float4*)(xrow + k0 + j * 4);
      } else {
#pragma unroll
        for (int j = 0; j < 8; ++j) {
          float e0 = 0.f, e1 = 0.f, e2 = 0.f, e3 = 0.f;
          if (rowok) {
            const int kc = k0 + j * 4;
            if (kc + 0 < lda) e0 = xrow[kc + 0];
            if (kc + 1 < lda) e1 = xrow[kc + 1];
            if (kc + 2 < lda) e2 = xrow[kc + 2];
            if (kc + 3 < lda) e3 = xrow[kc + 3];
          }
          float4 t; t.x = e0; t.y = e1; t.z = e2; t.w = e3;
          a4[j] = t;
        }
      }
    };
    auto writeA = [&](int d) {
#pragma unroll
      for (int j = 0; j < 4; ++j) {
        float4 lo = a4[2 * j], hi = a4[2 * j + 1];
        short8 v;
        v[0] = (short)f2bf(lo.x); v[1] = (short)f2bf(lo.y);
        v[2] = (short)f2bf(lo.z); v[3] = (short)f2bf(lo.w);
        v[4] = (short)f2bf(hi.x); v[5] = (short)f2bf(hi.y);
        v[6] = (short)f2bf(hi.z); v[7] = (short)f2bf(hi.w);
        const int ch = (ahalf * 4 + j) ^ (arow & 7);
        *(short8*)&smem[d * 16384 + arow * 64 + ch * 8] = v;
      }
    };

    // prologue: stage tile 0 (A via regs, B via gload_lds)
    issueA(0);
    stageU0(0, 0); stageU1(0, 0);
    asm volatile("s_waitcnt vmcnt(4)" ::: "memory");   // A f32 in regs
    writeA(0);
    __syncthreads();                                   // drains vm+lgkm, publishes LDS

    for (int kt = 0; kt < NKT; ++kt) {
      const int d = kt & 1;
      const bool more = (kt + 1 < NKT);
      short8 b[4][2];
#pragma unroll
      for (int j = 0; j < 4; ++j) { b[j][0] = readB(d, j, 0); b[j][1] = readB(d, j, 1); }
      short8 aC0k0 = readA(d, 0, 0), aC0k1 = readA(d, 0, 1);
      short8 aC1k0 = readA(d, 1, 0), aC1k1 = readA(d, 1, 1);
      if (more) {
        issueA(kt + 1);                 // 8 vm loads (first in FIFO)
        stageU0(d ^ 1, kt + 1);         // 2 gloads
        stageU1(d ^ 1, kt + 1);         // 2 gloads -> outstanding 12
      }
#pragma unroll
      for (int q = 0; q < 4; ++q) {
        short8 aN0k0, aN0k1, aN1k0, aN1k1;
        if (q < 3) {
          aN0k0 = readA(d, 2 * (q + 1), 0);     aN0k1 = readA(d, 2 * (q + 1), 1);
          aN1k0 = readA(d, 2 * (q + 1) + 1, 0); aN1k1 = readA(d, 2 * (q + 1) + 1, 1);
        }
        __builtin_amdgcn_s_setprio(1);
#pragma unroll
        for (int j = 0; j < 4; ++j) {
          acc[2 * q][j]     = __builtin_amdgcn_mfma_f32_16x16x32_bf16(aC0k0, b[j][0], acc[2 * q][j], 0, 0, 0);
          acc[2 * q + 1][j] = __builtin_amdgcn_mfma_f32_16x16x32_bf16(aC1k0, b[j][0], acc[2 * q + 1][j], 0, 0, 0);
        }
#pragma unroll
        for (int j = 0; j < 4; ++j) {
          acc[2 * q][j]     = __builtin_amdgcn_mfma_f32_16x16x32_bf16(aC0k1, b[j][1], acc[2 * q][j], 0, 0, 0);
          acc[2 * q + 1][j] = __builtin_amdgcn_mfma_f32_16x16x32_bf16(aC1k1, b[j][1], acc[2 * q + 1][j], 0, 0, 0);
        }
        __builtin_amdgcn_s_setprio(0);
        if (q < 3) { aC0k0 = aN0k0; aC0k1 = aN0k1; aC1k0 = aN1k0; aC1k1 = aN1k1; }
      }
      if (more) {
        asm volatile("s_waitcnt vmcnt(4)" ::: "memory");   // retire the 8 A loads
        writeA(d ^ 1);
      }
      asm volatile("s_waitcnt vmcnt(0) lgkmcnt(0)" ::: "memory");  // B gloads + A writes done
      __builtin_amdgcn_s_barrier();
    }
  } else {
    // ---- bf16-A gload path (round-12 verified, unchanged) ----
    const size_t abase = (size_t)(mblk + srow) * lda + clog * 8;
    auto stageA = [&](int d, int kt, int h) {
      u16* dst = smem + d * 16384 + h * 4096 + wave * 512;
      const u16* src = A + abase + (size_t)h * 64 * lda + kt * 64;
      __builtin_amdgcn_global_load_lds((const void*)src, (void*)dst, 16, 0, 0);
    };
    auto stageU2 = [&](int d, int kt) { stageA(d, kt, 0); stageA(d, kt, 2); };
    auto stageU3 = [&](int d, int kt) { stageA(d, kt, 1); stageA(d, kt, 3); };

    stageU0(0, 0); stageU1(0, 0); stageU2(0, 0); stageU3(0, 0);
    asm volatile("s_waitcnt vmcnt(2)" ::: "memory");
    __builtin_amdgcn_s_barrier();

    for (int kt = 0; kt < NKT; ++kt) {
      const int d = kt & 1;
      const bool more = (kt + 1 < NKT);
      short8 b[4][2];
#pragma unroll
      for (int j = 0; j < 4; ++j) { b[j][0] = readB(d, j, 0); b[j][1] = readB(d, j, 1); }
      {
        short8 a00 = readA(d, 0, 0), a01 = readA(d, 0, 1);
        short8 a10 = readA(d, 1, 0), a11 = readA(d, 1, 1);
        if (more) stageU0(d ^ 1, kt + 1);
        __builtin_amdgcn_s_setprio(1);
#pragma unroll
        for (int j = 0; j < 4; ++j) {
          acc[0][j] = __builtin_amdgcn_mfma_f32_16x16x32_bf16(a00, b[j][0], acc[0][j], 0, 0, 0);
          acc[1][j] = __builtin_amdgcn_mfma_f32_16x16x32_bf16(a10, b[j][0], acc[1][j], 0, 0, 0);
        }
#pragma unroll
        for (int j = 0; j < 4; ++j) {
          acc[0][j] = __builtin_amdgcn_mfma_f32_16x16x32_bf16(a01, b[j][1], acc[0][j], 0, 0, 0);
          acc[1][j] = __builtin_amdgcn_mfma_f32_16x16x32_bf16(a11, b[j][1], acc[1][j], 0, 0, 0);
        }
        __builtin_amdgcn_s_setprio(0);
      }
      {
        short8 a00 = readA(d, 2, 0), a01 = readA(d, 2, 1);
        short8 a10 = readA(d, 3, 0), a11 = readA(d, 3, 1);
        if (more) stageU1(d ^ 1, kt + 1);
        __builtin_amdgcn_s_setprio(1);
#pragma unroll
        for (int j = 0; j < 4; ++j) {
          acc[2][j] = __builtin_amdgcn_mfma_f32_16x16x32_bf16(a00, b[j][0], acc[2][j], 0, 0, 0);
          acc[3][j] = __builtin_amdgcn_mfma_f32_16x16x32_bf16(a10, b[j][0], acc[3][j], 0, 0, 0);
        }
#pragma unroll
        for (int j = 0; j < 4; ++j) {
          acc[2][j] = __builtin_amdgcn_mfma_f32_16x16x32_bf16(a01, b[j][1], acc[2][j], 0, 0, 0);
          acc[3][j] = __builtin_amdgcn_mfma_f32_16x16x32_bf16(a11, b[j][1], acc[3][j], 0, 0, 0);
        }
        __builtin_amdgcn_s_setprio(0);
      }
      if (more) asm volatile("s_waitcnt vmcnt(4)" ::: "memory");
      else      asm volatile("s_waitcnt vmcnt(0)" ::: "memory");
      __builtin_amdgcn_s_barrier();
      {
        short8 a00 = readA(d, 4, 0), a01 = readA(d, 4, 1);
        short8 a10 = readA(d, 5, 0), a11 = readA(d, 5, 1);
        if (more) stageU2(d ^ 1, kt + 1);
        __builtin_amdgcn_s_setprio(1);
#pragma unroll
        for (int j = 0; j < 4; ++j) {
          acc[4][j] = __builtin_amdgcn_mfma_f32_16x16x32_bf16(a00, b[j][0], acc[4][j], 0, 0, 0);
          acc[5][j] = __builtin_amdgcn_mfma_f32_16x16x32_bf16(a10, b[j][0], acc[5][j], 0, 0, 0);
        }
#pragma unroll
        for (int j = 0; j < 4; ++j) {
          acc[4][j] = __builtin_amdgcn_mfma_f32_16x16x32_bf16(a01, b[j][1], acc[4][j], 0, 0, 0);
          acc[5][j] = __builtin_amdgcn_mfma_f32_16x16x32_bf16(a11, b[j][1], acc[5][j], 0, 0, 0);
        }
        __builtin_amdgcn_s_setprio(0);
      }
      {
        short8 a00 = readA(d, 6, 0), a01 = readA(d, 6, 1);
        short8 a10 = readA(d, 7, 0), a11 = readA(d, 7, 1);
        if (more) stageU3(d ^ 1, kt + 1);
        __builtin_amdgcn_s_setprio(1);
#pragma unroll
        for (int j = 0; j < 4; ++j) {
          acc[6][j] = __builtin_amdgcn_mfma_f32_16x16x32_bf16(a00, b[j][0], acc[6][j], 0, 0, 0);
          acc[7][j] = __builtin_amdgcn_mfma_f32_16x16x32_bf16(a10, b[j][0], acc[7][j], 0, 0, 0);
        }
#pragma unroll
        for (int j = 0; j < 4; ++j) {
          acc[6][j] = __builtin_amdgcn_mfma_f32_16x16x32_bf16(a01, b[j][1], acc[6][j], 0, 0, 0);
          acc[7][j] = __builtin_amdgcn_mfma_f32_16x16x32_bf16(a11, b[j][1], acc[7][j], 0, 0, 0);
        }
        __builtin_amdgcn_s_setprio(0);
      }
      if (more) asm volatile("s_waitcnt vmcnt(2)" ::: "memory");
      __builtin_amdgcn_s_barrier();
    }
  }

  __syncthreads();   // full drain before LDS reuse

  // LDS-coalesced epilogue: 4 passes of 64 rows (all __syncthreads)
  float* ep = (float*)smem;
  const int ES = 260;
  const int colg = nblk + lane * 4;
  const bool second = (MODE == 0) && (nblk >= 512);
  float bv0 = 0.f, bv1 = 0.f, bv2 = 0.f, bv3 = 0.f;
  if (MODE == 0) {
    if (!second) { float4 b4 = *(const float4*)(bias + colg); bv0 = b4.x; bv1 = b4.y; bv2 = b4.z; bv3 = b4.w; }
  } else {
    if (colg + 3 < Nreal) {
      float4 b4 = *(const float4*)(bias + colg);
      bv0 = b4.x; bv1 = b4.y; bv2 = b4.z; bv3 = b4.w;
    } else {
      if (colg + 0 < Nreal) bv0 = bias[colg + 0];
      if (colg + 1 < Nreal) bv1 = bias[colg + 1];
      if (colg + 2 < Nreal) bv2 = bias[colg + 2];
      if (colg + 3 < Nreal) bv3 = bias[colg + 3];
    }
  }
#pragma unroll
  for (int p = 0; p < 4; ++p) {
    if (p) __syncthreads();
    if (wm == (p >> 1)) {
#pragma unroll
      for (int ii = 0; ii < 4; ++ii) {
        const int i = (p & 1) * 4 + ii;
        const int lrow0 = ii * 16 + kg * 4;
#pragma unroll
        for (int j = 0; j < 4; ++j) {
          const int colL = wn * 64 + j * 16 + ml;
#pragma unroll
          for (int r = 0; r < 4; ++r) ep[(lrow0 + r) * ES + colL] = acc[i][j][r];
        }
      }
    }
    __syncthreads();
#pragma unroll
    for (int it = 0; it < 8; ++it) {
      const int lrow = wave * 8 + it;
      const int grow = mblk + p * 64 + lrow;
      if (grow < M) {
        float v0 = ep[lrow * ES + lane * 4 + 0] + bv0;
        float v1 = ep[lrow * ES + lane * 4 + 1] + bv1;
        float v2 = ep[lrow * ES + lane * 4 + 2] + bv2;
        float v3 = ep[lrow * ES + lane * 4 + 3] + bv3;
        if (MODE == 0) {
          if (!second) { v0 = fmaxf(v0, 0.f); v1 = fmaxf(v1, 0.f); v2 = fmaxf(v2, 0.f); v3 = fmaxf(v3, 0.f); }
          u16* dst = (second ? (u16*)C2 : (u16*)C1) + (size_t)grow * 512 + (second ? colg - 512 : colg);
          short4v o;
          o[0] = (short)f2bf(v0); o[1] = (short)f2bf(v1);
          o[2] = (short)f2bf(v2); o[3] = (short)f2bf(v3);
          *(short4v*)dst = o;
        } else {
          float* dst = (float*)C1 + (size_t)grow * ldc + colg;
          if (colg + 3 < Nreal) {
            float4 v; v.x = v0; v.y = v1; v.z = v2; v.w = v3;
            *(float4*)dst = v;
          } else {
            if (colg + 0 < Nreal) dst[0] = v0;
            if (colg + 1 < Nreal) dst[1] = v1;
            if (colg + 2 < Nreal) dst[2] = v2;
            if (colg + 3 < Nreal) dst[3] = v3;
          }
        }
      }
    }
  }
}

// ---------------------------------------------------------------- fused SpMM + attention gate
template <int D>
__global__ __launch_bounds__(256) void spmm_attn(const int* __restrict__ rowptr,
                                                 const int* __restrict__ colidx,
                                                 const float* __restrict__ vals,
                                                 const u16* __restrict__ X,
                                                 const u16* __restrict__ T,
                                                 const float* __restrict__ a,
                                                 u16* __restrict__ emb) {
  constexpr int VE = D / 64;
  const int wave = threadIdx.x >> 6, lane = threadIdx.x & 63;
  const int row = blockIdx.x * 4 + wave;
  const int co = lane * VE;
  float h[VE];
#pragma unroll
  for (int j = 0; j < VE; ++j) h[j] = 0.f;
  const int s = rowptr[row], e = rowptr[row + 1];
  for (int base = s; base < e; base += 64) {
    const int n = min(64, e - base);
    int myc = 0; float myv = 0.f;
    if (base + lane < e) { myc = colidx[base + lane]; myv = vals[base + lane]; }
    for (int jj = 0; jj < n; ++jj) {
      const int c = __shfl(myc, jj);
      const float v = __shfl(myv, jj);
      const u16* xr = X + (size_t)c * D + co;
      if constexpr (VE == 8) {
        short8 x8 = *(const short8*)xr;
#pragma unroll
        for (int j = 0; j < 8; ++j) h[j] += v * bf2f((u16)x8[j]);
      } else if constexpr (VE == 4) {
        short4v x4 = *(const short4v*)xr;
#pragma unroll
        for (int j = 0; j < 4; ++j) h[j] += v * bf2f((u16)x4[j]);
      } else {
        u32 x2 = *(const u32*)xr;
        h[0] += v * bf2f((u16)(x2 & 0xffffu));
        h[1] += v * bf2f((u16)(x2 >> 16));
      }
    }
  }
#pragma unroll
  for (int j = 0; j < VE; ++j) h[j] = fmaxf(h[j], 0.f);   // relu on GCN branch

  float tv[VE];
  const u16* tr = T + (size_t)row * D + co;
  if constexpr (VE == 8) {
    short8 t8 = *(const short8*)tr;
#pragma unroll
    for (int j = 0; j < 8; ++j) tv[j] = bf2f((u16)t8[j]);
  } else if constexpr (VE == 4) {
    short4v t4 = *(const short4v*)tr;
#pragma unroll
    for (int j = 0; j < 4; ++j) tv[j] = bf2f((u16)t4[j]);
  } else {
    u32 t2 = *(const u32*)tr;
    tv[0] = bf2f((u16)(t2 & 0xffffu)); tv[1] = bf2f((u16)(t2 >> 16));
  }

  float wh = 0.f, wt = 0.f;
#pragma unroll
  for (int j = 0; j < VE; ++j) {
    float av = a[co + j];
    wh += av * h[j];
    wt += av * tv[j];
  }
  for (int off = 32; off; off >>= 1) {
    wh += __shfl_xor(wh, off);
    wt += __shfl_xor(wt, off);
  }
  float m = fmaxf(wh, wt);
  float e1 = expf(wh - m), e2 = expf(wt - m);
  float inv = 1.f / (e1 + e2);
  float b1 = e1 * inv, b2 = e2 * inv;
  u16* er = emb + (size_t)row * D + co;
  if constexpr (VE == 8) {
    short8 o;
#pragma unroll
    for (int j = 0; j < 8; ++j) o[j] = (short)f2bf(b1 * h[j] + b2 * tv[j]);
    *(short8*)er = o;
  } else if constexpr (VE == 4) {
    short4v o;
#pragma unroll
    for (int j = 0; j < 4; ++j) o[j] = (short)f2bf(b1 * h[j] + b2 * tv[j]);
    *(short4v*)er = o;
  } else {
    *(u32*)er = (u32)f2bf(b1 * h[0] + b2 * tv[0]) | ((u32)f2bf(b1 * h[1] + b2 * tv[1]) << 16);
  }
}

// ---------------------------------------------------------------- final-layer kernels
#define XROWS 12
__global__ __launch_bounds__(256) void xw5_blk(const u16* __restrict__ emb,
                                               const float* __restrict__ W5,
                                               u16* __restrict__ xw5, int Nrow) {
  __shared__ float W5s[128 * 20];     // 10 KB
  __shared__ u16 embs[XROWS * 128];   // 3 KB
  const int tid = threadIdx.x;
  const int row0 = blockIdx.x * XROWS;
  for (int i = tid; i < 2560; i += 256) W5s[i] = W5[i];
  if (tid < 192) {
    const int base = tid * 8;
    const int grow = row0 + base / 128;
    short8 v;
    if (grow < Nrow) v = *(const short8*)(emb + (size_t)row0 * 128 + base);
    else {
#pragma unroll
      for (int j = 0; j < 8; ++j) v[j] = 0;
    }
    *(short8*)(embs + base) = v;
  }
  __syncthreads();
  const int r = tid / 20;
  const int c = tid % 20;
  if (r < XROWS && tid < 240) {
    const int grow = row0 + r;
    if (grow < Nrow) {
      float acc = 0.f;
#pragma unroll 8
      for (int k = 0; k < 128; ++k) acc += bf2f(embs[r * 128 + k]) * W5s[k * 20 + c];
      xw5[(size_t)grow * 20 + c] = f2bf(acc);
    }
  }
}

__global__ __launch_bounds__(256) void spmm_out_blk(const int* __restrict__ rowptr,
                                                    const int* __restrict__ colidx,
                                                    const float* __restrict__ vals,
                                                    const u16* __restrict__ X,
                                                    float* __restrict__ Y, int Nrow) {
  const int tid = threadIdx.x;
  const int r = tid / 20;
  const int c = tid % 20;
  if (r >= XROWS || tid >= 240) return;
  const int row = blockIdx.x * XROWS + r;
  if (row >= Nrow) return;
  float acc = 0.f;
  const int s = rowptr[row], e = rowptr[row + 1];
  for (int i = s; i < e; ++i) {
    const int col = colidx[i];
    acc += vals[i] * bf2f(X[(size_t)col * 20 + c]);
  }
  Y[(size_t)row * 20 + c] = acc;
}

__global__ void sig_exp_kernel(const float* __restrict__ scale, const float* __restrict__ additive,
                               float* __restrict__ osig, float* __restrict__ oexp, int g) {
  int i = blockIdx.x * 256 + threadIdx.x;
  if (i < g) {
    osig[i] = 1.f / (1.f + expf(-scale[i]));
    oexp[i] = expf(additive[i]);
  }
}

// ---------------------------------------------------------------- launch
extern "C" void kernel_launch(void* const* d_in, const int* in_sizes, int n_in,
                              void* d_out, int out_size, void* d_ws, size_t ws_size,
                              hipStream_t stream) {
  (void)n_in; (void)out_size; (void)ws_size;
  const float* x      = (const float*)d_in[0];
  const int*   arows  = (const int*)d_in[1];
  const int*   acols  = (const int*)d_in[2];
  const float* avals  = (const float*)d_in[3];
  const float* W1     = (const float*)d_in[4];
  const float* W2     = (const float*)d_in[5];
  const float* W3     = (const float*)d_in[6];
  const float* W4     = (const float*)d_in[7];
  const float* W5     = (const float*)d_in[8];
  const float* enc1_w = (const float*)d_in[9],  *enc1_b = (const float*)d_in[10];
  const float* enc2_w = (const float*)d_in[11], *enc2_b = (const float*)d_in[12];
  const float* enc3_w = (const float*)d_in[13], *enc3_b = (const float*)d_in[14];
  const float* zl_w   = (const float*)d_in[15], *zl_b   = (const float*)d_in[16];
  const float* dec1_w = (const float*)d_in[17], *dec1_b = (const float*)d_in[18];
  const float* dec2_w = (const float*)d_in[19], *dec2_b = (const float*)d_in[20];
  const float* dec3_w = (const float*)d_in[21], *dec3_b = (const float*)d_in[22];
  const float* xbar_w = (const float*)d_in[23], *xbar_b = (const float*)d_in[24];
  const float* a1 = (const float*)d_in[25], *a2 = (const float*)d_in[26];
  const float* a3 = (const float*)d_in[27], *a4 = (const float*)d_in[28];
  const float* scale = (const float*)d_in[29], *additive = (const float*)d_in[30];

  const int E = in_sizes[1];
  const int N = 40000, G = 3000, Kx = 3008;
  const int Mp = 40192;          // 157*256 = 314*128

  float* out      = (float*)d_out;
  float* out_gcn  = out;                                   // [40000,20]
  float* out_xbar = out + (size_t)N * 20;                  // [40000,3000]
  float* out_sig  = out_xbar + (size_t)N * G;              // [3000]
  float* out_exp  = out_sig + G;                           // [3000]

  char* wsb = (char*)d_ws;
  size_t off = 0;
  auto alloc = [&](size_t b) -> void* {
    void* p = wsb + off;
    off = (off + b + 255) & ~(size_t)255;
    return p;
  };
  u16* t1    = (u16*)alloc((size_t)Mp * 512 * 2);
  u16* t2    = (u16*)alloc((size_t)Mp * 256 * 2);
  u16* t3    = (u16*)alloc((size_t)Mp * 128 * 2);
  u16* zb    = (u16*)alloc((size_t)Mp * 128 * 2);
  u16* dd1   = (u16*)alloc((size_t)Mp * 128 * 2);
  u16* dd2   = (u16*)alloc((size_t)Mp * 256 * 2);
  u16* dd3   = (u16*)alloc((size_t)Mp * 512 * 2);
  u16* xw    = (u16*)alloc((size_t)Mp * 512 * 2);
  u16* emb   = (u16*)alloc((size_t)Mp * 512 * 2);
  u16* xw5   = (u16*)alloc((size_t)N * 20 * 2);
  u16* catT  = (u16*)alloc((size_t)1024 * Kx * 2);   // enc1T rows 0-511, W1T rows 512-1023
  u16* enc2T = (u16*)alloc((size_t)256 * 512 * 2);
  u16* enc3T = (u16*)alloc((size_t)128 * 256 * 2);
  u16* zlT   = (u16*)alloc((size_t)128 * 128 * 2);
  u16* dec1T = (u16*)alloc((size_t)128 * 128 * 2);
  u16* dec2T = (u16*)alloc((size_t)256 * 128 * 2);
  u16* dec3T = (u16*)alloc((size_t)512 * 256 * 2);
  u16* xbarT = (u16*)alloc((size_t)3072 * 512 * 2);
  u16* W2T   = (u16*)alloc((size_t)256 * 512 * 2);
  u16* W3T   = (u16*)alloc((size_t)128 * 256 * 2);
  u16* W4T   = (u16*)alloc((size_t)128 * 128 * 2);
  int* counts = (int*)alloc((size_t)N * 4);
  int* rowptr = (int*)alloc((size_t)(N + 1) * 4);
  int* cursor = (int*)alloc((size_t)N * 4);
  int* colss  = (int*)alloc((size_t)E * 4);
  float* valss = (float*)alloc((size_t)E * 4);

  // weight conversions
  auto convw = [&](const float* W, u16* Wt, int K, int Nw, int Kp, int Np) {
    convw_kernel<<<dim3((Kp + 255) / 256, Np), 256, 0, stream>>>(W, Wt, K, Nw, Kp);
  };
  convw(enc1_w, catT,             3000, 512, Kx, 512);
  convw(W1,     catT + 512 * Kx,  3000, 512, Kx, 512);
  convw(enc2_w, enc2T, 512, 256, 512, 256);
  convw(enc3_w, enc3T, 256, 128, 256, 128);
  convw(zl_w,   zlT,   128, 128, 128, 128);
  convw(dec1_w, dec1T, 128, 128, 128, 128);
  convw(dec2_w, dec2T, 128, 256, 128, 256);
  convw(dec3_w, dec3T, 256, 512, 256, 512);
  convw(xbar_w, xbarT, 512, 3000, 512, 3072);
  convw(W2,     W2T,   512, 256, 512, 256);
  convw(W3,     W3T,   256, 128, 256, 128);
  convw(W4,     W4T,   128, 128, 128, 128);

  // CSR build
  zero_kernel<<<(N + 255) / 256, 256, 0, stream>>>(counts, N);
  count_kernel<<<(E + 255) / 256, 256, 0, stream>>>(arows, counts, E);
  scan_kernel<<<1, 1024, 0, stream>>>(counts, rowptr, cursor, N);
  scatter_kernel<<<(E + 255) / 256, 256, 0, stream>>>(arows, acols, avals, cursor, colss, valss, E);

  const int MT = 313;    // ceil(40000/128)
  const int MT2 = 157;   // ceil(40000/256)
  // fused enc1 + W1 (fp32-A reg-staged): x @ [enc1|W1] -> t1 (bias+relu) | xw
  gemm256p<0><<<MT2 * 4, 512, 0, stream>>>(
      (const u16*)x, 3000, catT, Kx, t1, xw, 512, enc1_b, N, 1024, Kx, MT2, 4);
  // rest of autoencoder (128^2 kernel)
  gemm_bf16<true, true, true, 32><<<MT * 2, 256, 0, stream>>>(
      t1, 512, enc2T, 512, t2, 256, enc2_b, N, 256, 512, MT, 2);
  gemm_bf16<true, true, true, 32><<<MT * 1, 256, 0, stream>>>(
      t2, 256, enc3T, 256, t3, 128, enc3_b, N, 128, 256, MT, 1);
  gemm_bf16<true, false, true, 32><<<MT * 1, 256, 0, stream>>>(
      t3, 128, zlT, 128, zb, 128, zl_b, N, 128, 128, MT, 1);
  gemm_bf16<true, true, true, 32><<<MT * 1, 256, 0, stream>>>(
      zb, 128, dec1T, 128, dd1, 128, dec1_b, N, 128, 128, MT, 1);
  gemm_bf16<true, true, true, 32><<<MT * 2, 256, 0, stream>>>(
      dd1, 128, dec2T, 128, dd2, 256, dec2_b, N, 256, 128, MT, 2);
  gemm_bf16<true, true, true, 32><<<MT * 4, 256, 0, stream>>>(
      dd2, 256, dec3T, 256, dd3, 512, dec3_b, N, 512, 256, MT, 4);
  // xbar (bf16-A path, fp32 LDS-coalesced epilogue), grid 157*12=1884
  gemm256p<1><<<MT2 * 12, 512, 0, stream>>>(
      dd3, 512, xbarT, 512, out_xbar, nullptr, 3000, xbar_b, N, 3000, 512, MT2, 12);

  // GCN stack: fused spmm+attention per layer
  spmm_attn<512><<<N / 4, 256, 0, stream>>>(rowptr, colss, valss, xw, t1, a1, emb);
  gemm_bf16<false, false, true, 32><<<MT * 2, 256, 0, stream>>>(
      emb, 512, W2T, 512, xw, 256, nullptr, N, 256, 512, MT, 2);
  spmm_attn<256><<<N / 4, 256, 0, stream>>>(rowptr, colss, valss, xw, t2, a2, emb);
  gemm_bf16<false, false, true, 32><<<MT * 1, 256, 0, stream>>>(
      emb, 256, W3T, 256, xw, 128, nullptr, N, 128, 256, MT, 1);
  spmm_attn<128><<<N / 4, 256, 0, stream>>>(rowptr, colss, valss, xw, t3, a3, emb);
  gemm_bf16<false, false, true, 32><<<MT * 1, 256, 0, stream>>>(
      emb, 128, W4T, 128, xw, 128, nullptr, N, 128, 128, MT, 1);
  spmm_attn<128><<<N / 4, 256, 0, stream>>>(rowptr, colss, valss, xw, zb, a4, emb);

  // layer 5 (no relu) -> d_out
  const int XB = (N + XROWS - 1) / XROWS;
  xw5_blk<<<XB, 256, 0, stream>>>(emb, W5, xw5, N);
  spmm_out_blk<<<XB, 256, 0, stream>>>(rowptr, colss, valss, xw5, out_gcn, N);

  sig_exp_kernel<<<(G + 255) / 256, 256, 0, stream>>>(scale, additive, out_sig, out_exp, G);
}

// Round 14
// 1286.751 us; speedup vs baseline: 1.0751x; 1.0751x over previous
//
#include <hip/hip_runtime.h>
#include <cmath>

typedef unsigned short u16;
typedef unsigned int u32;
typedef __attribute__((ext_vector_type(8))) short short8;   // 8 x bf16 (4 VGPRs)
typedef __attribute__((ext_vector_type(4))) short short4v;  // 4 x bf16
typedef __attribute__((ext_vector_type(4))) float f32x4;

__device__ __forceinline__ float bf2f(u16 h) {
  union { u32 u; float f; } v; v.u = ((u32)h) << 16; return v.f;
}
__device__ __forceinline__ u16 f2bf(float f) {
  union { float f; u32 u; } v; v.f = f;
  u32 u = v.u;
  u32 r = (u + 0x7FFFu + ((u >> 16) & 1u)) >> 16;   // RNE
  return (u16)r;
}

// ---------------------------------------------------------------- conversions
// x fp32 [40000,3000] -> bf16 [40192,3008]; thread: 2x float4 read, 1x short8 write
__global__ void convx_kernel(const float* __restrict__ x, u16* __restrict__ A0) {
  int idx = blockIdx.x * 256 + threadIdx.x;   // short8 slot
  int r = blockIdx.y;
  if (idx >= 376) return;
  short8 o;
  if (r < 40000 && idx < 375) {
    const float* src = x + (size_t)r * 3000 + idx * 8;
    float4 v0 = *(const float4*)src;
    float4 v1 = *(const float4*)(src + 4);
    o[0] = (short)f2bf(v0.x); o[1] = (short)f2bf(v0.y);
    o[2] = (short)f2bf(v0.z); o[3] = (short)f2bf(v0.w);
    o[4] = (short)f2bf(v1.x); o[5] = (short)f2bf(v1.y);
    o[6] = (short)f2bf(v1.z); o[7] = (short)f2bf(v1.w);
  } else {
#pragma unroll
    for (int j = 0; j < 8; ++j) o[j] = 0;
  }
  *(short8*)(A0 + (size_t)r * 3008 + idx * 8) = o;
}

__global__ void convw_kernel(const float* __restrict__ W, u16* __restrict__ Wt,
                             int K, int N, int Kp) {
  int k = blockIdx.x * 256 + threadIdx.x;
  int n = blockIdx.y;
  if (k >= Kp) return;
  float v = (k < K && n < N) ? W[(size_t)k * N + n] : 0.f;
  Wt[(size_t)n * Kp + k] = f2bf(v);
}

// ---------------------------------------------------------------- CSR build
__global__ void zero_kernel(int* p, int n) {
  int i = blockIdx.x * 256 + threadIdx.x;
  if (i < n) p[i] = 0;
}
__global__ void count_kernel(const int* __restrict__ rows, int* __restrict__ counts, int E) {
  int i = blockIdx.x * 256 + threadIdx.x;
  if (i < E) atomicAdd(&counts[rows[i]], 1);
}
__global__ __launch_bounds__(1024) void scan_kernel(const int* __restrict__ counts,
                                                    int* __restrict__ rowptr,
                                                    int* __restrict__ cursor, int n) {
  __shared__ int buf[1024];
  __shared__ int carry_s;
  int tid = threadIdx.x;
  if (tid == 0) carry_s = 0;
  __syncthreads();
  for (int base = 0; base < n; base += 1024) {
    int i = base + tid;
    int v = (i < n) ? counts[i] : 0;
    buf[tid] = v;
    __syncthreads();
    for (int off = 1; off < 1024; off <<= 1) {
      int tv = (tid >= off) ? buf[tid - off] : 0;
      __syncthreads();
      buf[tid] += tv;
      __syncthreads();
    }
    int incl = buf[tid];
    int carry = carry_s;
    if (i < n) { int ex = carry + incl - v; rowptr[i] = ex; cursor[i] = ex; }
    __syncthreads();
    if (tid == 1023) carry_s = carry + incl;
    __syncthreads();
  }
  if (tid == 0) rowptr[n] = carry_s;
}
__global__ void scatter_kernel(const int* __restrict__ rows, const int* __restrict__ cols,
                               const float* __restrict__ vals, int* __restrict__ cursor,
                               int* __restrict__ cols_s, float* __restrict__ vals_s, int E) {
  int i = blockIdx.x * 256 + threadIdx.x;
  if (i < E) {
    int r = rows[i];
    int p = atomicAdd(&cursor[r], 1);
    cols_s[p] = cols[i];
    vals_s[p] = vals[i];
  }
}

// ---------------------------------------------------------------- 128x128 bf16 GEMM (small layers)
#define BM 128
#define BN 128
#define BK 32

template <bool BIAS, bool RELU, bool OUTBF16, int CH>
__global__ __launch_bounds__(256, 2) void gemm_bf16(
    const u16* __restrict__ A, int lda, const u16* __restrict__ Bt, int ldb,
    void* __restrict__ C1, int ldc,
    const float* __restrict__ bias, int M, int Nreal, int K, int MT, int NT) {
  __shared__ __align__(16) u16 As[2][BM * BK];
  __shared__ __align__(16) u16 Bs[2][BN * BK];
  const int lin = blockIdx.x;
  const int per = CH * NT;
  const int g = lin / per;
  const int r0 = lin - g * per;
  const int bx0 = g * CH;
  const int cw = min(CH, MT - bx0);
  const int bx = bx0 + r0 % cw;
  const int by = r0 / cw;

  const int tid = threadIdx.x;
  const int lane = tid & 63;
  const int wave = tid >> 6;
  const int mblk = bx * BM;
  const int nblk = by * BN;
  const int wm = (wave & 1) * 64;
  const int wn = (wave >> 1) * 64;
  const int ml = lane & 15;
  const int kg = lane >> 4;

  f32x4 acc[4][4];
#pragma unroll
  for (int i = 0; i < 4; ++i)
#pragma unroll
    for (int j = 0; j < 4; ++j) acc[i][j] = (f32x4)(0.f);

  const int nk = K / BK;
  const int sr = tid >> 2;
  const int sc = (tid & 3) * 8;
  const u16* gA0 = A + (size_t)(mblk + sr) * lda + sc;
  const u16* gA1 = A + (size_t)(mblk + sr + 64) * lda + sc;
  const u16* gB0 = Bt + (size_t)(nblk + sr) * ldb + sc;
  const u16* gB1 = Bt + (size_t)(nblk + sr + 64) * ldb + sc;

  auto stage = [&](int buf, int kt) {
    const int ko = kt * BK;
    u16* lA = &As[buf][0] + wave * 512;
    u16* lB = &Bs[buf][0] + wave * 512;
    __builtin_amdgcn_global_load_lds((const void*)(gA0 + ko), (void*)lA, 16, 0, 0);
    __builtin_amdgcn_global_load_lds((const void*)(gA1 + ko), (void*)(lA + 2048), 16, 0, 0);
    __builtin_amdgcn_global_load_lds((const void*)(gB0 + ko), (void*)lB, 16, 0, 0);
    __builtin_amdgcn_global_load_lds((const void*)(gB1 + ko), (void*)(lB + 2048), 16, 0, 0);
  };

  stage(0, 0);
  asm volatile("s_waitcnt vmcnt(0)" ::: "memory");
  __syncthreads();

  int cur = 0;
  for (int kt = 0; kt < nk; ++kt) {
    if (kt + 1 < nk) stage(cur ^ 1, kt + 1);
    short8 af[4], bfr[4];
#pragma unroll
    for (int i = 0; i < 4; ++i) {
      af[i] = *(const short8*)&As[cur][(wm + i * 16 + ml) * BK + kg * 8];
      bfr[i] = *(const short8*)&Bs[cur][(wn + i * 16 + ml) * BK + kg * 8];
    }
#pragma unroll
    for (int i = 0; i < 4; ++i)
#pragma unroll
      for (int j = 0; j < 4; ++j)
        acc[i][j] = __builtin_amdgcn_mfma_f32_16x16x32_bf16(af[i], bfr[j], acc[i][j], 0, 0, 0);
    asm volatile("s_waitcnt vmcnt(0)" ::: "memory");
    __syncthreads();
    cur ^= 1;
  }

#pragma unroll
  for (int i = 0; i < 4; ++i) {
    const int row0 = mblk + wm + i * 16 + kg * 4;
#pragma unroll
    for (int j = 0; j < 4; ++j) {
      const int col = nblk + wn + j * 16 + ml;
      if (col < Nreal) {
        float bv = BIAS ? bias[col] : 0.f;
#pragma unroll
        for (int r = 0; r < 4; ++r) {
          const int row = row0 + r;
          if (row < M) {
            float v = acc[i][j][r] + bv;
            if (RELU) v = fmaxf(v, 0.f);
            if (OUTBF16)
              ((u16*)C1)[(size_t)row * ldc + col] = f2bf(v);
            else
              ((float*)C1)[(size_t)row * ldc + col] = v;
          }
        }
      }
    }
  }
}

// ---------------------------------------------------------------- 256x256 8-wave pipelined GEMM
// (verified round 11/12: enc 278us @ MfmaUtil 38.8%, 0 bank conflicts)
// LDS layout in u16 ELEMENT offsets: A(d) at d*16384, B(d) at 32768 + d*16384.
template <int MODE>
__global__ __launch_bounds__(512, 1) void gemm256p(
    const u16* __restrict__ A, int lda, const u16* __restrict__ Bt, int ldb,
    void* __restrict__ C1, void* __restrict__ C2, int ldc,
    const float* __restrict__ bias, int M, int Nreal, int K, int MT2, int NT) {
  __shared__ __align__(16) u16 smem[2 * 2 * 256 * 64];   // 128 KiB
  const int tid = threadIdx.x;
  const int lane = tid & 63;
  const int wave = tid >> 6;
  const int wm = wave >> 2;        // 0..1
  const int wn = wave & 3;         // 0..3
  const int ml = lane & 15;
  const int kg = lane >> 4;

  const int grp = blockIdx.x / (8 * NT);
  const int rr = blockIdx.x % (8 * NT);
  const int nb = min(8, MT2 - grp * 8);
  const int bx = grp * 8 + rr % nb;
  const int by = rr / nb;
  const int mblk = bx * 256;
  const int nblk = by * 256;

  f32x4 acc[8][4];
#pragma unroll
  for (int i = 0; i < 8; ++i)
#pragma unroll
    for (int j = 0; j < 4; ++j) acc[i][j] = (f32x4)(0.f);

  const int srow = tid >> 3;
  const int clog = (tid & 7) ^ (srow & 7);
  const size_t abase = (size_t)(mblk + srow) * lda + clog * 8;
  const size_t bbase = (size_t)(nblk + srow) * ldb + clog * 8;
  const int NKT = K / 64;

  auto stageA = [&](int d, int kt, int h) {
    u16* dst = smem + d * 16384 + h * 4096 + wave * 512;
    const u16* src = A + abase + (size_t)h * 64 * lda + kt * 64;
    __builtin_amdgcn_global_load_lds((const void*)src, (void*)dst, 16, 0, 0);
  };
  auto stageB = [&](int d, int kt, int h) {
    u16* dst = smem + 32768 + d * 16384 + h * 4096 + wave * 512;
    const u16* src = Bt + bbase + (size_t)h * 64 * ldb + kt * 64;
    __builtin_amdgcn_global_load_lds((const void*)src, (void*)dst, 16, 0, 0);
  };
  auto stageU0 = [&](int d, int kt) { stageB(d, kt, 0); stageB(d, kt, 1); };
  auto stageU1 = [&](int d, int kt) { stageB(d, kt, 2); stageB(d, kt, 3); };
  auto stageU2 = [&](int d, int kt) { stageA(d, kt, 0); stageA(d, kt, 2); };
  auto stageU3 = [&](int d, int kt) { stageA(d, kt, 1); stageA(d, kt, 3); };
  auto readA = [&](int d, int im, int kk) -> short8 {
    const int r = wm * 128 + im * 16 + ml;
    const int ch = (kk * 4 + kg) ^ (r & 7);
    return *(const short8*)&smem[d * 16384 + r * 64 + ch * 8];
  };
  auto readB = [&](int d, int j, int kk) -> short8 {
    const int r = wn * 64 + j * 16 + ml;
    const int ch = (kk * 4 + kg) ^ (r & 7);
    return *(const short8*)&smem[32768 + d * 16384 + r * 64 + ch * 8];
  };

  stageU0(0, 0); stageU1(0, 0); stageU2(0, 0); stageU3(0, 0);
  asm volatile("s_waitcnt vmcnt(2)" ::: "memory");
  __builtin_amdgcn_s_barrier();

  for (int kt = 0; kt < NKT; ++kt) {
    const int d = kt & 1;
    const bool more = (kt + 1 < NKT);
    short8 b[4][2];
#pragma unroll
    for (int j = 0; j < 4; ++j) { b[j][0] = readB(d, j, 0); b[j][1] = readB(d, j, 1); }
    {
      short8 a00 = readA(d, 0, 0), a01 = readA(d, 0, 1);
      short8 a10 = readA(d, 1, 0), a11 = readA(d, 1, 1);
      if (more) stageU0(d ^ 1, kt + 1);
      __builtin_amdgcn_s_setprio(1);
#pragma unroll
      for (int j = 0; j < 4; ++j) {
        acc[0][j] = __builtin_amdgcn_mfma_f32_16x16x32_bf16(a00, b[j][0], acc[0][j], 0, 0, 0);
        acc[1][j] = __builtin_amdgcn_mfma_f32_16x16x32_bf16(a10, b[j][0], acc[1][j], 0, 0, 0);
      }
#pragma unroll
      for (int j = 0; j < 4; ++j) {
        acc[0][j] = __builtin_amdgcn_mfma_f32_16x16x32_bf16(a01, b[j][1], acc[0][j], 0, 0, 0);
        acc[1][j] = __builtin_amdgcn_mfma_f32_16x16x32_bf16(a11, b[j][1], acc[1][j], 0, 0, 0);
      }
      __builtin_amdgcn_s_setprio(0);
    }
    {
      short8 a00 = readA(d, 2, 0), a01 = readA(d, 2, 1);
      short8 a10 = readA(d, 3, 0), a11 = readA(d, 3, 1);
      if (more) stageU1(d ^ 1, kt + 1);
      __builtin_amdgcn_s_setprio(1);
#pragma unroll
      for (int j = 0; j < 4; ++j) {
        acc[2][j] = __builtin_amdgcn_mfma_f32_16x16x32_bf16(a00, b[j][0], acc[2][j], 0, 0, 0);
        acc[3][j] = __builtin_amdgcn_mfma_f32_16x16x32_bf16(a10, b[j][0], acc[3][j], 0, 0, 0);
      }
#pragma unroll
      for (int j = 0; j < 4; ++j) {
        acc[2][j] = __builtin_amdgcn_mfma_f32_16x16x32_bf16(a01, b[j][1], acc[2][j], 0, 0, 0);
        acc[3][j] = __builtin_amdgcn_mfma_f32_16x16x32_bf16(a11, b[j][1], acc[3][j], 0, 0, 0);
      }
      __builtin_amdgcn_s_setprio(0);
    }
    if (more) asm volatile("s_waitcnt vmcnt(4)" ::: "memory");
    else      asm volatile("s_waitcnt vmcnt(0)" ::: "memory");
    __builtin_amdgcn_s_barrier();
    {
      short8 a00 = readA(d, 4, 0), a01 = readA(d, 4, 1);
      short8 a10 = readA(d, 5, 0), a11 = readA(d, 5, 1);
      if (more) stageU2(d ^ 1, kt + 1);
      __builtin_amdgcn_s_setprio(1);
#pragma unroll
      for (int j = 0; j < 4; ++j) {
        acc[4][j] = __builtin_amdgcn_mfma_f32_16x16x32_bf16(a00, b[j][0], acc[4][j], 0, 0, 0);
        acc[5][j] = __builtin_amdgcn_mfma_f32_16x16x32_bf16(a10, b[j][0], acc[5][j], 0, 0, 0);
      }
#pragma unroll
      for (int j = 0; j < 4; ++j) {
        acc[4][j] = __builtin_amdgcn_mfma_f32_16x16x32_bf16(a01, b[j][1], acc[4][j], 0, 0, 0);
        acc[5][j] = __builtin_amdgcn_mfma_f32_16x16x32_bf16(a11, b[j][1], acc[5][j], 0, 0, 0);
      }
      __builtin_amdgcn_s_setprio(0);
    }
    {
      short8 a00 = readA(d, 6, 0), a01 = readA(d, 6, 1);
      short8 a10 = readA(d, 7, 0), a11 = readA(d, 7, 1);
      if (more) stageU3(d ^ 1, kt + 1);
      __builtin_amdgcn_s_setprio(1);
#pragma unroll
      for (int j = 0; j < 4; ++j) {
        acc[6][j] = __builtin_amdgcn_mfma_f32_16x16x32_bf16(a00, b[j][0], acc[6][j], 0, 0, 0);
        acc[7][j] = __builtin_amdgcn_mfma_f32_16x16x32_bf16(a10, b[j][0], acc[7][j], 0, 0, 0);
      }
#pragma unroll
      for (int j = 0; j < 4; ++j) {
        acc[6][j] = __builtin_amdgcn_mfma_f32_16x16x32_bf16(a01, b[j][1], acc[6][j], 0, 0, 0);
        acc[7][j] = __builtin_amdgcn_mfma_f32_16x16x32_bf16(a11, b[j][1], acc[7][j], 0, 0, 0);
      }
      __builtin_amdgcn_s_setprio(0);
    }
    if (more) asm volatile("s_waitcnt vmcnt(2)" ::: "memory");
    __builtin_amdgcn_s_barrier();
  }

  __syncthreads();   // full drain before LDS reuse

  // LDS-coalesced epilogue: 4 passes of 64 rows (all __syncthreads)
  float* ep = (float*)smem;
  const int ES = 260;
  const int colg = nblk + lane * 4;
  const bool second = (MODE == 0) && (nblk >= 512);
  float bv0 = 0.f, bv1 = 0.f, bv2 = 0.f, bv3 = 0.f;
  if (MODE == 0) {
    if (!second) { float4 b4 = *(const float4*)(bias + colg); bv0 = b4.x; bv1 = b4.y; bv2 = b4.z; bv3 = b4.w; }
  } else {
    if (colg + 3 < Nreal) {
      float4 b4 = *(const float4*)(bias + colg);
      bv0 = b4.x; bv1 = b4.y; bv2 = b4.z; bv3 = b4.w;
    } else {
      if (colg + 0 < Nreal) bv0 = bias[colg + 0];
      if (colg + 1 < Nreal) bv1 = bias[colg + 1];
      if (colg + 2 < Nreal) bv2 = bias[colg + 2];
      if (colg + 3 < Nreal) bv3 = bias[colg + 3];
    }
  }
#pragma unroll
  for (int p = 0; p < 4; ++p) {
    if (p) __syncthreads();
    if (wm == (p >> 1)) {
#pragma unroll
      for (int ii = 0; ii < 4; ++ii) {
        const int i = (p & 1) * 4 + ii;
        const int lrow0 = ii * 16 + kg * 4;
#pragma unroll
        for (int j = 0; j < 4; ++j) {
          const int colL = wn * 64 + j * 16 + ml;
#pragma unroll
          for (int r = 0; r < 4; ++r) ep[(lrow0 + r) * ES + colL] = acc[i][j][r];
        }
      }
    }
    __syncthreads();
#pragma unroll
    for (int it = 0; it < 8; ++it) {
      const int lrow = wave * 8 + it;
      const int grow = mblk + p * 64 + lrow;
      if (grow < M) {
        float v0 = ep[lrow * ES + lane * 4 + 0] + bv0;
        float v1 = ep[lrow * ES + lane * 4 + 1] + bv1;
        float v2 = ep[lrow * ES + lane * 4 + 2] + bv2;
        float v3 = ep[lrow * ES + lane * 4 + 3] + bv3;
        if (MODE == 0) {
          if (!second) { v0 = fmaxf(v0, 0.f); v1 = fmaxf(v1, 0.f); v2 = fmaxf(v2, 0.f); v3 = fmaxf(v3, 0.f); }
          u16* dst = (second ? (u16*)C2 : (u16*)C1) + (size_t)grow * 512 + (second ? colg - 512 : colg);
          short4v o;
          o[0] = (short)f2bf(v0); o[1] = (short)f2bf(v1);
          o[2] = (short)f2bf(v2); o[3] = (short)f2bf(v3);
          *(short4v*)dst = o;
        } else {
          float* dst = (float*)C1 + (size_t)grow * ldc + colg;
          if (colg + 3 < Nreal) {
            float4 v; v.x = v0; v.y = v1; v.z = v2; v.w = v3;
            *(float4*)dst = v;
          } else {
            if (colg + 0 < Nreal) dst[0] = v0;
            if (colg + 1 < Nreal) dst[1] = v1;
            if (colg + 2 < Nreal) dst[2] = v2;
            if (colg + 3 < Nreal) dst[3] = v3;
          }
        }
      }
    }
  }
}

// ---------------------------------------------------------------- fused SpMM + attention gate
template <int D>
__global__ __launch_bounds__(256) void spmm_attn(const int* __restrict__ rowptr,
                                                 const int* __restrict__ colidx,
                                                 const float* __restrict__ vals,
                                                 const u16* __restrict__ X,
                                                 const u16* __restrict__ T,
                                                 const float* __restrict__ a,
                                                 u16* __restrict__ emb) {
  constexpr int VE = D / 64;
  const int wave = threadIdx.x >> 6, lane = threadIdx.x & 63;
  const int row = blockIdx.x * 4 + wave;
  const int co = lane * VE;
  float h[VE];
#pragma unroll
  for (int j = 0; j < VE; ++j) h[j] = 0.f;
  const int s = rowptr[row], e = rowptr[row + 1];
  for (int base = s; base < e; base += 64) {
    const int n = min(64, e - base);
    int myc = 0; float myv = 0.f;
    if (base + lane < e) { myc = colidx[base + lane]; myv = vals[base + lane]; }
    for (int jj = 0; jj < n; ++jj) {
      const int c = __shfl(myc, jj);
      const float v = __shfl(myv, jj);
      const u16* xr = X + (size_t)c * D + co;
      if constexpr (VE == 8) {
        short8 x8 = *(const short8*)xr;
#pragma unroll
        for (int j = 0; j < 8; ++j) h[j] += v * bf2f((u16)x8[j]);
      } else if constexpr (VE == 4) {
        short4v x4 = *(const short4v*)xr;
#pragma unroll
        for (int j = 0; j < 4; ++j) h[j] += v * bf2f((u16)x4[j]);
      } else {
        u32 x2 = *(const u32*)xr;
        h[0] += v * bf2f((u16)(x2 & 0xffffu));
        h[1] += v * bf2f((u16)(x2 >> 16));
      }
    }
  }
#pragma unroll
  for (int j = 0; j < VE; ++j) h[j] = fmaxf(h[j], 0.f);   // relu on GCN branch

  float tv[VE];
  const u16* tr = T + (size_t)row * D + co;
  if constexpr (VE == 8) {
    short8 t8 = *(const short8*)tr;
#pragma unroll
    for (int j = 0; j < 8; ++j) tv[j] = bf2f((u16)t8[j]);
  } else if constexpr (VE == 4) {
    short4v t4 = *(const short4v*)tr;
#pragma unroll
    for (int j = 0; j < 4; ++j) tv[j] = bf2f((u16)t4[j]);
  } else {
    u32 t2 = *(const u32*)tr;
    tv[0] = bf2f((u16)(t2 & 0xffffu)); tv[1] = bf2f((u16)(t2 >> 16));
  }

  float wh = 0.f, wt = 0.f;
#pragma unroll
  for (int j = 0; j < VE; ++j) {
    float av = a[co + j];
    wh += av * h[j];
    wt += av * tv[j];
  }
  for (int off = 32; off; off >>= 1) {
    wh += __shfl_xor(wh, off);
    wt += __shfl_xor(wt, off);
  }
  float m = fmaxf(wh, wt);
  float e1 = expf(wh - m), e2 = expf(wt - m);
  float inv = 1.f / (e1 + e2);
  float b1 = e1 * inv, b2 = e2 * inv;
  u16* er = emb + (size_t)row * D + co;
  if constexpr (VE == 8) {
    short8 o;
#pragma unroll
    for (int j = 0; j < 8; ++j) o[j] = (short)f2bf(b1 * h[j] + b2 * tv[j]);
    *(short8*)er = o;
  } else if constexpr (VE == 4) {
    short4v o;
#pragma unroll
    for (int j = 0; j < 4; ++j) o[j] = (short)f2bf(b1 * h[j] + b2 * tv[j]);
    *(short4v*)er = o;
  } else {
    *(u32*)er = (u32)f2bf(b1 * h[0] + b2 * tv[0]) | ((u32)f2bf(b1 * h[1] + b2 * tv[1]) << 16);
  }
}

// ---------------------------------------------------------------- final-layer kernels
#define XROWS 12
__global__ __launch_bounds__(256) void xw5_blk(const u16* __restrict__ emb,
                                               const float* __restrict__ W5,
                                               u16* __restrict__ xw5, int Nrow) {
  __shared__ float W5s[128 * 20];     // 10 KB
  __shared__ u16 embs[XROWS * 128];   // 3 KB
  const int tid = threadIdx.x;
  const int row0 = blockIdx.x * XROWS;
  for (int i = tid; i < 2560; i += 256) W5s[i] = W5[i];
  if (tid < 192) {
    const int base = tid * 8;
    const int grow = row0 + base / 128;
    short8 v;
    if (grow < Nrow) v = *(const short8*)(emb + (size_t)row0 * 128 + base);
    else {
#pragma unroll
      for (int j = 0; j < 8; ++j) v[j] = 0;
    }
    *(short8*)(embs + base) = v;
  }
  __syncthreads();
  const int r = tid / 20;
  const int c = tid % 20;
  if (r < XROWS && tid < 240) {
    const int grow = row0 + r;
    if (grow < Nrow) {
      float acc = 0.f;
#pragma unroll 8
      for (int k = 0; k < 128; ++k) acc += bf2f(embs[r * 128 + k]) * W5s[k * 20 + c];
      xw5[(size_t)grow * 20 + c] = f2bf(acc);
    }
  }
}

__global__ __launch_bounds__(256) void spmm_out_blk(const int* __restrict__ rowptr,
                                                    const int* __restrict__ colidx,
                                                    const float* __restrict__ vals,
                                                    const u16* __restrict__ X,
                                                    float* __restrict__ Y, int Nrow) {
  const int tid = threadIdx.x;
  const int r = tid / 20;
  const int c = tid % 20;
  if (r >= XROWS || tid >= 240) return;
  const int row = blockIdx.x * XROWS + r;
  if (row >= Nrow) return;
  float acc = 0.f;
  const int s = rowptr[row], e = rowptr[row + 1];
  for (int i = s; i < e; ++i) {
    const int col = colidx[i];
    acc += vals[i] * bf2f(X[(size_t)col * 20 + c]);
  }
  Y[(size_t)row * 20 + c] = acc;
}

__global__ void sig_exp_kernel(const float* __restrict__ scale, const float* __restrict__ additive,
                               float* __restrict__ osig, float* __restrict__ oexp, int g) {
  int i = blockIdx.x * 256 + threadIdx.x;
  if (i < g) {
    osig[i] = 1.f / (1.f + expf(-scale[i]));
    oexp[i] = expf(additive[i]);
  }
}

// ---------------------------------------------------------------- launch
extern "C" void kernel_launch(void* const* d_in, const int* in_sizes, int n_in,
                              void* d_out, int out_size, void* d_ws, size_t ws_size,
                              hipStream_t stream) {
  (void)n_in; (void)out_size; (void)ws_size;
  const float* x      = (const float*)d_in[0];
  const int*   arows  = (const int*)d_in[1];
  const int*   acols  = (const int*)d_in[2];
  const float* avals  = (const float*)d_in[3];
  const float* W1     = (const float*)d_in[4];
  const float* W2     = (const float*)d_in[5];
  const float* W3     = (const float*)d_in[6];
  const float* W4     = (const float*)d_in[7];
  const float* W5     = (const float*)d_in[8];
  const float* enc1_w = (const float*)d_in[9],  *enc1_b = (const float*)d_in[10];
  const float* enc2_w = (const float*)d_in[11], *enc2_b = (const float*)d_in[12];
  const float* enc3_w = (const float*)d_in[13], *enc3_b = (const float*)d_in[14];
  const float* zl_w   = (const float*)d_in[15], *zl_b   = (const float*)d_in[16];
  const float* dec1_w = (const float*)d_in[17], *dec1_b = (const float*)d_in[18];
  const float* dec2_w = (const float*)d_in[19], *dec2_b = (const float*)d_in[20];
  const float* dec3_w = (const float*)d_in[21], *dec3_b = (const float*)d_in[22];
  const float* xbar_w = (const float*)d_in[23], *xbar_b = (const float*)d_in[24];
  const float* a1 = (const float*)d_in[25], *a2 = (const float*)d_in[26];
  const float* a3 = (const float*)d_in[27], *a4 = (const float*)d_in[28];
  const float* scale = (const float*)d_in[29], *additive = (const float*)d_in[30];

  const int E = in_sizes[1];
  const int N = 40000, G = 3000, Kx = 3008;
  const int Mp = 40192;          // 157*256 = 314*128

  float* out      = (float*)d_out;
  float* out_gcn  = out;                                   // [40000,20]
  float* out_xbar = out + (size_t)N * 20;                  // [40000,3000]
  float* out_sig  = out_xbar + (size_t)N * G;              // [3000]
  float* out_exp  = out_sig + G;                           // [3000]

  char* wsb = (char*)d_ws;
  size_t off = 0;
  auto alloc = [&](size_t b) -> void* {
    void* p = wsb + off;
    off = (off + b + 255) & ~(size_t)255;
    return p;
  };
  u16* A0    = (u16*)alloc((size_t)Mp * Kx * 2);
  u16* t1    = (u16*)alloc((size_t)Mp * 512 * 2);
  u16* t2    = (u16*)alloc((size_t)Mp * 256 * 2);
  u16* t3    = (u16*)alloc((size_t)Mp * 128 * 2);
  u16* zb    = (u16*)alloc((size_t)Mp * 128 * 2);
  u16* dd1   = (u16*)alloc((size_t)Mp * 128 * 2);
  u16* dd2   = (u16*)alloc((size_t)Mp * 256 * 2);
  u16* dd3   = (u16*)alloc((size_t)Mp * 512 * 2);
  u16* xw    = (u16*)alloc((size_t)Mp * 512 * 2);
  u16* emb   = (u16*)alloc((size_t)Mp * 512 * 2);
  u16* xw5   = (u16*)alloc((size_t)N * 20 * 2);
  u16* catT  = (u16*)alloc((size_t)1024 * Kx * 2);   // enc1T rows 0-511, W1T rows 512-1023
  u16* enc2T = (u16*)alloc((size_t)256 * 512 * 2);
  u16* enc3T = (u16*)alloc((size_t)128 * 256 * 2);
  u16* zlT   = (u16*)alloc((size_t)128 * 128 * 2);
  u16* dec1T = (u16*)alloc((size_t)128 * 128 * 2);
  u16* dec2T = (u16*)alloc((size_t)256 * 128 * 2);
  u16* dec3T = (u16*)alloc((size_t)512 * 256 * 2);
  u16* xbarT = (u16*)alloc((size_t)3072 * 512 * 2);
  u16* W2T   = (u16*)alloc((size_t)256 * 512 * 2);
  u16* W3T   = (u16*)alloc((size_t)128 * 256 * 2);
  u16* W4T   = (u16*)alloc((size_t)128 * 128 * 2);
  int* counts = (int*)alloc((size_t)N * 4);
  int* rowptr = (int*)alloc((size_t)(N + 1) * 4);
  int* cursor = (int*)alloc((size_t)N * 4);
  int* colss  = (int*)alloc((size_t)E * 4);
  float* valss = (float*)alloc((size_t)E * 4);

  // conversions
  convx_kernel<<<dim3(2, Mp), 256, 0, stream>>>(x, A0);
  auto convw = [&](const float* W, u16* Wt, int K, int Nw, int Kp, int Np) {
    convw_kernel<<<dim3((Kp + 255) / 256, Np), 256, 0, stream>>>(W, Wt, K, Nw, Kp);
  };
  convw(enc1_w, catT,             3000, 512, Kx, 512);
  convw(W1,     catT + 512 * Kx,  3000, 512, Kx, 512);
  convw(enc2_w, enc2T, 512, 256, 512, 256);
  convw(enc3_w, enc3T, 256, 128, 256, 128);
  convw(zl_w,   zlT,   128, 128, 128, 128);
  convw(dec1_w, dec1T, 128, 128, 128, 128);
  convw(dec2_w, dec2T, 128, 256, 128, 256);
  convw(dec3_w, dec3T, 256, 512, 256, 512);
  convw(xbar_w, xbarT, 512, 3000, 512, 3072);
  convw(W2,     W2T,   512, 256, 512, 256);
  convw(W3,     W3T,   256, 128, 256, 128);
  convw(W4,     W4T,   128, 128, 128, 128);

  // CSR build
  zero_kernel<<<(N + 255) / 256, 256, 0, stream>>>(counts, N);
  count_kernel<<<(E + 255) / 256, 256, 0, stream>>>(arows, counts, E);
  scan_kernel<<<1, 1024, 0, stream>>>(counts, rowptr, cursor, N);
  scatter_kernel<<<(E + 255) / 256, 256, 0, stream>>>(arows, acols, avals, cursor, colss, valss, E);

  const int MT = 313;    // ceil(40000/128)
  const int MT2 = 157;   // ceil(40000/256)
  // fused enc1 + W1 (256^2 pipelined): A0 @ [enc1|W1] -> t1 (bias+relu) | xw
  gemm256p<0><<<MT2 * 4, 512, 0, stream>>>(
      A0, Kx, catT, Kx, t1, xw, 512, enc1_b, N, 1024, Kx, MT2, 4);
  // rest of autoencoder (128^2 kernel)
  gemm_bf16<true, true, true, 32><<<MT * 2, 256, 0, stream>>>(
      t1, 512, enc2T, 512, t2, 256, enc2_b, N, 256, 512, MT, 2);
  gemm_bf16<true, true, true, 32><<<MT * 1, 256, 0, stream>>>(
      t2, 256, enc3T, 256, t3, 128, enc3_b, N, 128, 256, MT, 1);
  gemm_bf16<true, false, true, 32><<<MT * 1, 256, 0, stream>>>(
      t3, 128, zlT, 128, zb, 128, zl_b, N, 128, 128, MT, 1);
  gemm_bf16<true, true, true, 32><<<MT * 1, 256, 0, stream>>>(
      zb, 128, dec1T, 128, dd1, 128, dec1_b, N, 128, 128, MT, 1);
  gemm_bf16<true, true, true, 32><<<MT * 2, 256, 0, stream>>>(
      dd1, 128, dec2T, 128, dd2, 256, dec2_b, N, 256, 128, MT, 2);
  gemm_bf16<true, true, true, 32><<<MT * 4, 256, 0, stream>>>(
      dd2, 256, dec3T, 256, dd3, 512, dec3_b, N, 512, 256, MT, 4);
  // xbar (256^2 pipelined, fp32 LDS-coalesced epilogue), grid 157*12=1884
  gemm256p<1><<<MT2 * 12, 512, 0, stream>>>(
      dd3, 512, xbarT, 512, out_xbar, nullptr, 3000, xbar_b, N, 3000, 512, MT2, 12);

  // GCN stack: fused spmm+attention per layer
  spmm_attn<512><<<N / 4, 256, 0, stream>>>(rowptr, colss, valss, xw, t1, a1, emb);
  gemm_bf16<false, false, true, 32><<<MT * 2, 256, 0, stream>>>(
      emb, 512, W2T, 512, xw, 256, nullptr, N, 256, 512, MT, 2);
  spmm_attn<256><<<N / 4, 256, 0, stream>>>(rowptr, colss, valss, xw, t2, a2, emb);
  gemm_bf16<false, false, true, 32><<<MT * 1, 256, 0, stream>>>(
      emb, 256, W3T, 256, xw, 128, nullptr, N, 128, 256, MT, 1);
  spmm_attn<128><<<N / 4, 256, 0, stream>>>(rowptr, colss, valss, xw, t3, a3, emb);
  gemm_bf16<false, false, true, 32><<<MT * 1, 256, 0, stream>>>(
      emb, 128, W4T, 128, xw, 128, nullptr, N, 128, 128, MT, 1);
  spmm_attn<128><<<N / 4, 256, 0, stream>>>(rowptr, colss, valss, xw, zb, a4, emb);

  // layer 5 (no relu) -> d_out
  const int XB = (N + XROWS - 1) / XROWS;
  xw5_blk<<<XB, 256, 0, stream>>>(emb, W5, xw5, N);
  spmm_out_blk<<<XB, 256, 0, stream>>>(rowptr, colss, valss, xw5, out_gcn, N);

  sig_exp_kernel<<<(G + 255) / 256, 256, 0, stream>>>(scale, additive, out_sig, out_exp, G);
}